// Round 5
// baseline (736.214 us; speedup 1.0000x reference)
//
#include <hip/hip_runtime.h>
#include <cstdint>

#define NHEAD 8
#define D1 64      // H1*C1
#define IN_F 128
#define NEG 0.2f
#define NBINS 256  // loss partial-sum bins

// ---------------- Kernel A: h1 = feat @ W1, a_src1/a_dst1 dots ----------------
__global__ __launch_bounds__(256) void k_gemm1(
    const float* __restrict__ feat,
    const float* __restrict__ W1,
    const float* __restrict__ att_s,
    const float* __restrict__ att_d,
    float* __restrict__ h1, float* __restrict__ a_src, float* __restrict__ a_dst,
    int N)
{
    __shared__ float ldsW[IN_F * D1];   // 32 KB
    __shared__ float ldsF[4][IN_F];     // 2 KB
    const int tid = threadIdx.x;
    for (int i = tid; i < IN_F * D1; i += 256) ldsW[i] = W1[i];
    const int r = tid >> 6, j = tid & 63;
    const float asw = att_s[j];
    const float adw = att_d[j];
    const int base = blockIdx.x * 4;
    for (int i = tid; i < 4 * IN_F; i += 256) {
        int rr = i >> 7, k = i & 127;
        int n = base + rr;
        ldsF[rr][k] = (n < N) ? feat[(size_t)n * IN_F + k] : 0.f;
    }
    __syncthreads();
    const int n = base + r;
    if (n < N) {
        float acc = 0.f;
        #pragma unroll 8
        for (int k = 0; k < IN_F; ++k)
            acc = fmaf(ldsF[r][k], ldsW[k * D1 + j], acc);
        h1[(size_t)n * D1 + j] = acc;
        float ps = acc * asw, pd = acc * adw;
        ps += __shfl_xor(ps, 1); pd += __shfl_xor(pd, 1);
        ps += __shfl_xor(ps, 2); pd += __shfl_xor(pd, 2);
        ps += __shfl_xor(ps, 4); pd += __shfl_xor(pd, 4);
        if ((j & 7) == 0) {
            int h = j >> 3;
            a_src[n * NHEAD + h] = ps;
            a_dst[n * NHEAD + h] = pd;
        }
    }
}

// ---------------- CSR build: histogram / scan / fill ----------------
__global__ __launch_bounds__(256) void k_hist(
    const int* __restrict__ dst, int* __restrict__ deg, int E)
{
    int e = blockIdx.x * 256 + threadIdx.x;
    if (e < E) atomicAdd(&deg[dst[e]], 1);
}

__device__ __forceinline__ int block_incl_scan(int v, int tid, int* lds4)
{
    int lane = tid & 63, w = tid >> 6;
    #pragma unroll
    for (int off = 1; off < 64; off <<= 1) {
        int t = __shfl_up(v, off);
        if (lane >= off) v += t;
    }
    if (lane == 63) lds4[w] = v;
    __syncthreads();
    int add = 0;
    #pragma unroll
    for (int i = 0; i < 4; ++i)
        if (i < w) add += lds4[i];
    __syncthreads();
    return v + add;
}

__global__ __launch_bounds__(256) void k_scan1(
    const int* __restrict__ deg, int* __restrict__ locx, int* __restrict__ bsum, int N)
{
    __shared__ int lds4[4];
    int i = blockIdx.x * 256 + threadIdx.x;
    int v = (i < N) ? deg[i] : 0;
    int incl = block_incl_scan(v, threadIdx.x, lds4);
    if (i < N) locx[i] = incl - v;
    if (threadIdx.x == 255) bsum[blockIdx.x] = incl;
}

__global__ __launch_bounds__(256) void k_scan2(int* __restrict__ bsum, int nblk)
{
    __shared__ int lds4[4];
    __shared__ int carry;
    if (threadIdx.x == 0) carry = 0;
    __syncthreads();
    for (int base = 0; base < nblk; base += 256) {
        int i = base + threadIdx.x;
        int v = (i < nblk) ? bsum[i] : 0;
        int incl = block_incl_scan(v, threadIdx.x, lds4);
        int c = carry;
        __syncthreads();
        if (i < nblk) bsum[i] = incl - v + c;   // exclusive offset of block i
        if (threadIdx.x == 255) carry = c + incl;
        __syncthreads();
    }
}

__global__ __launch_bounds__(256) void k_scan3(
    const int* __restrict__ locx, const int* __restrict__ bsum,
    int* __restrict__ offs, int* __restrict__ cur, int N)
{
    int i = blockIdx.x * 256 + threadIdx.x;
    if (i < N) {
        int o = locx[i] + bsum[i >> 8];
        offs[i] = o;
        cur[i] = o;
    }
}

__global__ __launch_bounds__(256) void k_fill(
    const int* __restrict__ src, const int* __restrict__ dst,
    int* __restrict__ cur, int* __restrict__ srcs, int E)
{
    int e = blockIdx.x * 256 + threadIdx.x;
    if (e < E) {
        int p = atomicAdd(&cur[dst[e]], 1);
        srcs[p] = src[e];
    }
}

// ---------------- Layer-1 aggregation, dst-grouped, fused norm+bias+ELU ----------------
// 8-edge chunks: lane j precomputes ex for (edge j&7, head j>>3); group-of-8
// shfl_xor gives per-head denominators; inner loop is 2 shfl + gather + fma.
__global__ __launch_bounds__(256) void k_agg1(
    const int* __restrict__ deg, const int* __restrict__ offs,
    const int* __restrict__ srcs,
    const float* __restrict__ a_s, const float* __restrict__ a_d,
    const float* __restrict__ h1, const float* __restrict__ b1,
    float* __restrict__ x, int N)
{
    const int tid = threadIdx.x, w = tid >> 6, j = tid & 63;
    const int c = j & 7, hh = j >> 3;      // producer: edge-slot c, head hh
    const int n = blockIdx.x * 4 + w;
    if (n >= N) return;
    const int rlen = deg[n], row = offs[n];
    const float ad = a_d[n * NHEAD + hh];  // consumer head == producer head
    float acc = 0.f, den = 0.f;
    for (int base = 0; base < rlen; base += 8) {
        int m = rlen - base; if (m > 8) m = 8;
        int myS = 0; float ex = 0.f;
        if (c < m) {
            myS = srcs[row + base + c];
            float v = a_s[myS * NHEAD + hh] + ad;
            v = v > 0.f ? v : NEG * v;
            ex = expf(v);
        }
        float ds = ex;                      // per-head denom: reduce within aligned 8-lane group
        ds += __shfl_xor(ds, 1);
        ds += __shfl_xor(ds, 2);
        ds += __shfl_xor(ds, 4);
        den += ds;
        for (int k = 0; k < m; ++k) {
            int s = __shfl(myS, k);                      // lane k holds edge k's src
            float exk = __shfl(ex, (j & 0x38) | k);      // lane hh*8+k holds ex(edge k, head hh)
            acc = fmaf(exk, h1[(size_t)s * D1 + j], acc);
        }
    }
    float o = acc / den + b1[j];
    x[(size_t)n * D1 + j] = o > 0.f ? o : expm1f(o);
}

// ---------------- Kernel D: h2 = x @ W2, a_src2/a_dst2 ----------------
__global__ __launch_bounds__(256) void k_gemm2(
    const float* __restrict__ x,
    const float* __restrict__ W2,
    const float* __restrict__ att_s,
    const float* __restrict__ att_d,
    float* __restrict__ h2, float* __restrict__ a_src, float* __restrict__ a_dst,
    int N)
{
    __shared__ float ldsW[64 * 64];   // 16 KB
    __shared__ float ldsX[4][64];
    const int tid = threadIdx.x;
    for (int i = tid; i < 64 * 64; i += 256) ldsW[i] = W2[i];
    const int r = tid >> 6, j = tid & 63;
    const float asw = att_s[j];
    const float adw = att_d[j];
    const int base = blockIdx.x * 4;
    const int n = base + r;
    ldsX[r][j] = (n < N) ? x[(size_t)n * 64 + j] : 0.f;
    __syncthreads();
    if (n < N) {
        float acc = 0.f;
        #pragma unroll 8
        for (int k = 0; k < 64; ++k)
            acc = fmaf(ldsX[r][k], ldsW[k * 64 + j], acc);
        h2[(size_t)n * 64 + j] = acc;
        float ps = acc * asw, pd = acc * adw;
        #pragma unroll
        for (int off = 1; off < 64; off <<= 1) {
            ps += __shfl_xor(ps, off);
            pd += __shfl_xor(pd, off);
        }
        if (j == 0) { a_src[n] = ps; a_dst[n] = pd; }
    }
}

// ---------------- Layer-2 aggregation + bias + log-softmax + argmax + NLL ----------------
// 64-edge chunks: lane j precomputes ex for edge j; full-wave shfl_xor reduce
// for the denominator; inner loop is 2 shfl + gather + fma.
__global__ __launch_bounds__(256) void k_agg2(
    const int* __restrict__ deg, const int* __restrict__ offs,
    const int* __restrict__ srcs,
    const float* __restrict__ a_s, const float* __restrict__ a_d,
    const float* __restrict__ h2, const float* __restrict__ b2,
    const int* __restrict__ label,
    float* __restrict__ dout, double* __restrict__ bins, int N)
{
    __shared__ float snll[4];
    const int tid = threadIdx.x, w = tid >> 6, j = tid & 63;
    const int n = blockIdx.x * 4 + w;
    if (j == 0) snll[w] = 0.f;
    if (n < N) {
        const int rlen = deg[n], row = offs[n];
        const float ad = a_d[n];
        float acc = 0.f, den = 0.f;
        for (int base = 0; base < rlen; base += 64) {
            int m = rlen - base; if (m > 64) m = 64;
            int myS = 0; float ex = 0.f;
            if (j < m) {
                myS = srcs[row + base + j];
                float v = a_s[myS] + ad;
                v = v > 0.f ? v : NEG * v;
                ex = expf(v);
            }
            float ds = ex;
            #pragma unroll
            for (int off = 1; off < 64; off <<= 1) ds += __shfl_xor(ds, off);
            den += ds;
            for (int k = 0; k < m; ++k) {
                int s = __shfl(myS, k);
                float exk = __shfl(ex, k);
                acc = fmaf(exk, h2[(size_t)s * 64 + j], acc);
            }
        }
        float sc = acc / den + b2[j];
        // argmax, lowest-index tie-break (np.argmax)
        float mv = sc; int mi = j;
        #pragma unroll
        for (int off = 1; off < 64; off <<= 1) {
            float ov = __shfl_xor(mv, off);
            int oi = __shfl_xor(mi, off);
            if (ov > mv || (ov == mv && oi < mi)) { mv = ov; mi = oi; }
        }
        float se = expf(sc - mv);
        #pragma unroll
        for (int off = 1; off < 64; off <<= 1) se += __shfl_xor(se, off);
        int lab = label[n];
        float sl = __shfl(sc, lab);
        if (j == 0) {
            snll[w] = mv + logf(se) - sl;
            dout[1 + n] = (float)mi;
            dout[1 + (size_t)N + n] = (float)lab;
        }
    }
    __syncthreads();
    if (tid == 0) {
        double bsum = (double)snll[0] + (double)snll[1]
                    + (double)snll[2] + (double)snll[3];
        atomicAdd(&bins[blockIdx.x & (NBINS - 1)], bsum);
    }
}

// Single block of 256: reduce NBINS doubles -> loss
__global__ __launch_bounds__(256) void k_loss(
    const double* __restrict__ bins, float* __restrict__ dout, int N)
{
    __shared__ double sw[4];
    const int tid = threadIdx.x;
    double v = bins[tid];
    #pragma unroll
    for (int off = 1; off < 64; off <<= 1) v += __shfl_xor(v, off);
    if ((tid & 63) == 0) sw[tid >> 6] = v;
    __syncthreads();
    if (tid == 0)
        dout[0] = (float)((sw[0] + sw[1] + sw[2] + sw[3]) / (double)N);
}

extern "C" void kernel_launch(void* const* d_in, const int* in_sizes, int n_in,
                              void* d_out, int out_size, void* d_ws, size_t ws_size,
                              hipStream_t stream)
{
    const float* feat   = (const float*)d_in[1];
    const int*   edge   = (const int*)d_in[2];
    const int*   label  = (const int*)d_in[4];
    const float* W1     = (const float*)d_in[5];
    const float* att_s1 = (const float*)d_in[6];
    const float* att_d1 = (const float*)d_in[7];
    const float* b1     = (const float*)d_in[8];
    const float* W2     = (const float*)d_in[9];
    const float* att_s2 = (const float*)d_in[10];
    const float* att_d2 = (const float*)d_in[11];
    const float* b2     = (const float*)d_in[12];

    const int N = in_sizes[0];
    const int E = in_sizes[2] / 2;
    const int* src = edge;
    const int* dst = edge + E;

    // workspace layout (~66 MB):
    float* bufA = (float*)d_ws;               // N*64: h1, later reused as h2
    float* bufB = bufA + (size_t)N * 64;      // N*64: x (elu output)
    float* a_s1 = bufB + (size_t)N * 64;      // N*8 (layer2 reuses: a_s2=[0..N), a_d2=[N..2N))
    float* a_d1 = a_s1 + (size_t)N * 8;       // N*8
    int*   deg  = (int*)(a_d1 + (size_t)N * 8); // N
    int*   offs = deg + N;                    // N
    int*   cur  = offs + N;                   // N
    int*   srcs = cur + N;                    // E
    int*   locx = srcs + E;                   // N (scan scratch)
    int*   bsum = locx + N;                   // nblk (scan scratch)
    double* bins = (double*)(((uintptr_t)(bsum + ((N + 255) / 256) + 1) + 7) & ~(uintptr_t)7);

    float* a_s2 = a_s1;
    float* a_d2 = a_s1 + N;

    float* out = (float*)d_out;

    const int nblk = (N + 255) / 256;
    const int egrid = (E + 255) / 256;

    hipMemsetAsync(deg, 0, (size_t)N * sizeof(int), stream);
    hipMemsetAsync(bins, 0, NBINS * sizeof(double), stream);

    // CSR build (graph identical for both layers; rebuilt every call — no static state)
    k_hist <<<egrid, 256, 0, stream>>>(dst, deg, E);
    k_scan1<<<nblk, 256, 0, stream>>>(deg, locx, bsum, N);
    k_scan2<<<1, 256, 0, stream>>>(bsum, nblk);
    k_scan3<<<nblk, 256, 0, stream>>>(locx, bsum, offs, cur, N);
    k_fill <<<egrid, 256, 0, stream>>>(src, dst, cur, srcs, E);

    k_gemm1<<<(N + 3) / 4, 256, 0, stream>>>(feat, W1, att_s1, att_d1, bufA, a_s1, a_d1, N);
    k_agg1 <<<(N + 3) / 4, 256, 0, stream>>>(deg, offs, srcs, a_s1, a_d1, bufA, b1, bufB, N);
    k_gemm2<<<(N + 3) / 4, 256, 0, stream>>>(bufB, W2, att_s2, att_d2, bufA, a_s2, a_d2, N);
    k_agg2 <<<(N + 3) / 4, 256, 0, stream>>>(deg, offs, srcs, a_s2, a_d2, bufA, b2, label,
                                             out, bins, N);
    k_loss <<<1, 256, 0, stream>>>(bins, out, N);
}

// Round 6
// 645.522 us; speedup vs baseline: 1.1405x; 1.1405x over previous
//
#include <hip/hip_runtime.h>
#include <cstdint>

#define NHEAD 8
#define D1 64      // H1*C1
#define IN_F 128
#define NEG 0.2f
#define NBINS 256  // loss partial-sum bins

// ---------------- Kernel A: h1 = feat @ W1, a_src1/a_dst1 dots ----------------
__global__ __launch_bounds__(256) void k_gemm1(
    const float* __restrict__ feat,
    const float* __restrict__ W1,
    const float* __restrict__ att_s,
    const float* __restrict__ att_d,
    float* __restrict__ h1, float* __restrict__ a_src, float* __restrict__ a_dst,
    int N)
{
    __shared__ float ldsW[IN_F * D1];   // 32 KB
    __shared__ float ldsF[4][IN_F];     // 2 KB
    const int tid = threadIdx.x;
    for (int i = tid; i < IN_F * D1; i += 256) ldsW[i] = W1[i];
    const int r = tid >> 6, j = tid & 63;
    const float asw = att_s[j];
    const float adw = att_d[j];
    const int base = blockIdx.x * 4;
    for (int i = tid; i < 4 * IN_F; i += 256) {
        int rr = i >> 7, k = i & 127;
        int n = base + rr;
        ldsF[rr][k] = (n < N) ? feat[(size_t)n * IN_F + k] : 0.f;
    }
    __syncthreads();
    const int n = base + r;
    if (n < N) {
        float acc = 0.f;
        #pragma unroll 8
        for (int k = 0; k < IN_F; ++k)
            acc = fmaf(ldsF[r][k], ldsW[k * D1 + j], acc);
        h1[(size_t)n * D1 + j] = acc;
        float ps = acc * asw, pd = acc * adw;
        ps += __shfl_xor(ps, 1); pd += __shfl_xor(pd, 1);
        ps += __shfl_xor(ps, 2); pd += __shfl_xor(pd, 2);
        ps += __shfl_xor(ps, 4); pd += __shfl_xor(pd, 4);
        if ((j & 7) == 0) {
            int h = j >> 3;
            a_src[n * NHEAD + h] = ps;
            a_dst[n * NHEAD + h] = pd;
        }
    }
}

// ---------------- CSR build: histogram / scan / fill ----------------
__global__ __launch_bounds__(256) void k_hist(
    const int* __restrict__ dst, int* __restrict__ deg, int E)
{
    int e = blockIdx.x * 256 + threadIdx.x;
    if (e < E) atomicAdd(&deg[dst[e]], 1);
}

__device__ __forceinline__ int block_incl_scan(int v, int tid, int* lds4)
{
    int lane = tid & 63, w = tid >> 6;
    #pragma unroll
    for (int off = 1; off < 64; off <<= 1) {
        int t = __shfl_up(v, off);
        if (lane >= off) v += t;
    }
    if (lane == 63) lds4[w] = v;
    __syncthreads();
    int add = 0;
    #pragma unroll
    for (int i = 0; i < 4; ++i)
        if (i < w) add += lds4[i];
    __syncthreads();
    return v + add;
}

__global__ __launch_bounds__(256) void k_scan1(
    const int* __restrict__ deg, int* __restrict__ locx, int* __restrict__ bsum, int N)
{
    __shared__ int lds4[4];
    int i = blockIdx.x * 256 + threadIdx.x;
    int v = (i < N) ? deg[i] : 0;
    int incl = block_incl_scan(v, threadIdx.x, lds4);
    if (i < N) locx[i] = incl - v;
    if (threadIdx.x == 255) bsum[blockIdx.x] = incl;
}

__global__ __launch_bounds__(256) void k_scan2(int* __restrict__ bsum, int nblk)
{
    __shared__ int lds4[4];
    __shared__ int carry;
    if (threadIdx.x == 0) carry = 0;
    __syncthreads();
    for (int base = 0; base < nblk; base += 256) {
        int i = base + threadIdx.x;
        int v = (i < nblk) ? bsum[i] : 0;
        int incl = block_incl_scan(v, threadIdx.x, lds4);
        int c = carry;
        __syncthreads();
        if (i < nblk) bsum[i] = incl - v + c;   // exclusive offset of block i
        if (threadIdx.x == 255) carry = c + incl;
        __syncthreads();
    }
}

__global__ __launch_bounds__(256) void k_scan3(
    const int* __restrict__ locx, const int* __restrict__ bsum,
    int* __restrict__ offs, int* __restrict__ cur, int N)
{
    int i = blockIdx.x * 256 + threadIdx.x;
    if (i < N) {
        int o = locx[i] + bsum[i >> 8];
        offs[i] = o;
        cur[i] = o;
    }
}

__global__ __launch_bounds__(256) void k_fill(
    const int* __restrict__ src, const int* __restrict__ dst,
    int* __restrict__ cur, int* __restrict__ srcs, int E)
{
    int e = blockIdx.x * 256 + threadIdx.x;
    if (e < E) {
        int p = atomicAdd(&cur[dst[e]], 1);
        srcs[p] = src[e];
    }
}

// ---------------- Layer-1 aggregation, dst-grouped, fused norm+bias+ELU ----------------
// 8-edge chunks: lane j precomputes ex for (edge j&7, head j>>3). Full chunks take
// an unrolled path issuing 8 independent gathers (8x memory-level parallelism);
// round-5 lesson: runtime-trip inner loop = 1 load in flight = latency-bound.
__global__ __launch_bounds__(256) void k_agg1(
    const int* __restrict__ deg, const int* __restrict__ offs,
    const int* __restrict__ srcs,
    const float* __restrict__ a_s, const float* __restrict__ a_d,
    const float* __restrict__ h1, const float* __restrict__ b1,
    float* __restrict__ x, int N)
{
    const int tid = threadIdx.x, w = tid >> 6, j = tid & 63;
    const int c = j & 7, hh = j >> 3;      // producer: edge-slot c, head hh
    const int n = blockIdx.x * 4 + w;
    if (n >= N) return;
    const int rlen = deg[n], row = offs[n];
    const float ad = a_d[n * NHEAD + hh];
    float acc0 = 0.f, acc1 = 0.f, den = 0.f;
    for (int base = 0; base < rlen; base += 8) {
        int m = rlen - base; if (m > 8) m = 8;
        int myS = 0; float ex = 0.f;
        if (c < m) {
            myS = srcs[row + base + c];
            float v = a_s[myS * NHEAD + hh] + ad;
            v = v > 0.f ? v : NEG * v;
            ex = expf(v);
        }
        float ds = ex;                      // per-head denom: aligned 8-lane group reduce
        ds += __shfl_xor(ds, 1);
        ds += __shfl_xor(ds, 2);
        ds += __shfl_xor(ds, 4);
        den += ds;
        if (m == 8) {
            int   s8[8]; float e8[8], l8[8];
            #pragma unroll
            for (int k = 0; k < 8; ++k) {
                s8[k] = __shfl(myS, k);
                e8[k] = __shfl(ex, (j & 0x38) | k);
            }
            #pragma unroll
            for (int k = 0; k < 8; ++k)
                l8[k] = h1[(size_t)s8[k] * D1 + j];   // 8 loads in flight
            #pragma unroll
            for (int k = 0; k < 8; ++k) {
                if (k & 1) acc1 = fmaf(e8[k], l8[k], acc1);
                else       acc0 = fmaf(e8[k], l8[k], acc0);
            }
        } else {
            for (int k = 0; k < m; ++k) {
                int s = __shfl(myS, k);
                float exk = __shfl(ex, (j & 0x38) | k);
                if (k & 1) acc1 = fmaf(exk, h1[(size_t)s * D1 + j], acc1);
                else       acc0 = fmaf(exk, h1[(size_t)s * D1 + j], acc0);
            }
        }
    }
    float o = (acc0 + acc1) / den + b1[j];
    x[(size_t)n * D1 + j] = o > 0.f ? o : expm1f(o);
}

// ---------------- Kernel D: h2 = x @ W2, a_src2/a_dst2 ----------------
__global__ __launch_bounds__(256) void k_gemm2(
    const float* __restrict__ x,
    const float* __restrict__ W2,
    const float* __restrict__ att_s,
    const float* __restrict__ att_d,
    float* __restrict__ h2, float* __restrict__ a_src, float* __restrict__ a_dst,
    int N)
{
    __shared__ float ldsW[64 * 64];   // 16 KB
    __shared__ float ldsX[4][64];
    const int tid = threadIdx.x;
    for (int i = tid; i < 64 * 64; i += 256) ldsW[i] = W2[i];
    const int r = tid >> 6, j = tid & 63;
    const float asw = att_s[j];
    const float adw = att_d[j];
    const int base = blockIdx.x * 4;
    const int n = base + r;
    ldsX[r][j] = (n < N) ? x[(size_t)n * 64 + j] : 0.f;
    __syncthreads();
    if (n < N) {
        float acc = 0.f;
        #pragma unroll 8
        for (int k = 0; k < 64; ++k)
            acc = fmaf(ldsX[r][k], ldsW[k * 64 + j], acc);
        h2[(size_t)n * 64 + j] = acc;
        float ps = acc * asw, pd = acc * adw;
        #pragma unroll
        for (int off = 1; off < 64; off <<= 1) {
            ps += __shfl_xor(ps, off);
            pd += __shfl_xor(pd, off);
        }
        if (j == 0) { a_src[n] = ps; a_dst[n] = pd; }
    }
}

// ---------------- Layer-2 aggregation + bias + log-softmax + argmax + NLL ----------------
// 64-edge producer chunks; consumer drains in unrolled groups of 8 gathers.
__global__ __launch_bounds__(256) void k_agg2(
    const int* __restrict__ deg, const int* __restrict__ offs,
    const int* __restrict__ srcs,
    const float* __restrict__ a_s, const float* __restrict__ a_d,
    const float* __restrict__ h2, const float* __restrict__ b2,
    const int* __restrict__ label,
    float* __restrict__ dout, double* __restrict__ bins, int N)
{
    __shared__ float snll[4];
    const int tid = threadIdx.x, w = tid >> 6, j = tid & 63;
    const int n = blockIdx.x * 4 + w;
    if (j == 0) snll[w] = 0.f;
    if (n < N) {
        const int rlen = deg[n], row = offs[n];
        const float ad = a_d[n];
        float acc0 = 0.f, acc1 = 0.f, den = 0.f;
        for (int base = 0; base < rlen; base += 64) {
            int m = rlen - base; if (m > 64) m = 64;
            int myS = 0; float ex = 0.f;
            if (j < m) {
                myS = srcs[row + base + j];
                float v = a_s[myS] + ad;
                v = v > 0.f ? v : NEG * v;
                ex = expf(v);
            }
            float ds = ex;
            #pragma unroll
            for (int off = 1; off < 64; off <<= 1) ds += __shfl_xor(ds, off);
            den += ds;
            int k = 0;
            for (; k + 8 <= m; k += 8) {
                int   s8[8]; float e8[8], l8[8];
                #pragma unroll
                for (int i = 0; i < 8; ++i) {
                    s8[i] = __shfl(myS, k + i);
                    e8[i] = __shfl(ex, k + i);
                }
                #pragma unroll
                for (int i = 0; i < 8; ++i)
                    l8[i] = h2[(size_t)s8[i] * 64 + j];   // 8 loads in flight
                #pragma unroll
                for (int i = 0; i < 8; ++i) {
                    if (i & 1) acc1 = fmaf(e8[i], l8[i], acc1);
                    else       acc0 = fmaf(e8[i], l8[i], acc0);
                }
            }
            for (; k < m; ++k) {
                int s = __shfl(myS, k);
                float exk = __shfl(ex, k);
                if (k & 1) acc1 = fmaf(exk, h2[(size_t)s * 64 + j], acc1);
                else       acc0 = fmaf(exk, h2[(size_t)s * 64 + j], acc0);
            }
        }
        float sc = (acc0 + acc1) / den + b2[j];
        // argmax, lowest-index tie-break (np.argmax)
        float mv = sc; int mi = j;
        #pragma unroll
        for (int off = 1; off < 64; off <<= 1) {
            float ov = __shfl_xor(mv, off);
            int oi = __shfl_xor(mi, off);
            if (ov > mv || (ov == mv && oi < mi)) { mv = ov; mi = oi; }
        }
        float se = expf(sc - mv);
        #pragma unroll
        for (int off = 1; off < 64; off <<= 1) se += __shfl_xor(se, off);
        int lab = label[n];
        float sl = __shfl(sc, lab);
        if (j == 0) {
            snll[w] = mv + logf(se) - sl;
            dout[1 + n] = (float)mi;
            dout[1 + (size_t)N + n] = (float)lab;
        }
    }
    __syncthreads();
    if (tid == 0) {
        double bsum = (double)snll[0] + (double)snll[1]
                    + (double)snll[2] + (double)snll[3];
        atomicAdd(&bins[blockIdx.x & (NBINS - 1)], bsum);
    }
}

// Single block of 256: reduce NBINS doubles -> loss
__global__ __launch_bounds__(256) void k_loss(
    const double* __restrict__ bins, float* __restrict__ dout, int N)
{
    __shared__ double sw[4];
    const int tid = threadIdx.x;
    double v = bins[tid];
    #pragma unroll
    for (int off = 1; off < 64; off <<= 1) v += __shfl_xor(v, off);
    if ((tid & 63) == 0) sw[tid >> 6] = v;
    __syncthreads();
    if (tid == 0)
        dout[0] = (float)((sw[0] + sw[1] + sw[2] + sw[3]) / (double)N);
}

extern "C" void kernel_launch(void* const* d_in, const int* in_sizes, int n_in,
                              void* d_out, int out_size, void* d_ws, size_t ws_size,
                              hipStream_t stream)
{
    const float* feat   = (const float*)d_in[1];
    const int*   edge   = (const int*)d_in[2];
    const int*   label  = (const int*)d_in[4];
    const float* W1     = (const float*)d_in[5];
    const float* att_s1 = (const float*)d_in[6];
    const float* att_d1 = (const float*)d_in[7];
    const float* b1     = (const float*)d_in[8];
    const float* W2     = (const float*)d_in[9];
    const float* att_s2 = (const float*)d_in[10];
    const float* att_d2 = (const float*)d_in[11];
    const float* b2     = (const float*)d_in[12];

    const int N = in_sizes[0];
    const int E = in_sizes[2] / 2;
    const int* src = edge;
    const int* dst = edge + E;

    // workspace layout (~66 MB):
    float* bufA = (float*)d_ws;               // N*64: h1, later reused as h2
    float* bufB = bufA + (size_t)N * 64;      // N*64: x (elu output)
    float* a_s1 = bufB + (size_t)N * 64;      // N*8 (layer2 reuses: a_s2=[0..N), a_d2=[N..2N))
    float* a_d1 = a_s1 + (size_t)N * 8;       // N*8
    int*   deg  = (int*)(a_d1 + (size_t)N * 8); // N
    int*   offs = deg + N;                    // N
    int*   cur  = offs + N;                   // N
    int*   srcs = cur + N;                    // E
    int*   locx = srcs + E;                   // N (scan scratch)
    int*   bsum = locx + N;                   // nblk (scan scratch)
    double* bins = (double*)(((uintptr_t)(bsum + ((N + 255) / 256) + 1) + 7) & ~(uintptr_t)7);

    float* a_s2 = a_s1;
    float* a_d2 = a_s1 + N;

    float* out = (float*)d_out;

    const int nblk = (N + 255) / 256;
    const int egrid = (E + 255) / 256;

    hipMemsetAsync(deg, 0, (size_t)N * sizeof(int), stream);
    hipMemsetAsync(bins, 0, NBINS * sizeof(double), stream);

    // CSR build (graph identical for both layers; rebuilt every call — no static state)
    k_hist <<<egrid, 256, 0, stream>>>(dst, deg, E);
    k_scan1<<<nblk, 256, 0, stream>>>(deg, locx, bsum, N);
    k_scan2<<<1, 256, 0, stream>>>(bsum, nblk);
    k_scan3<<<nblk, 256, 0, stream>>>(locx, bsum, offs, cur, N);
    k_fill <<<egrid, 256, 0, stream>>>(src, dst, cur, srcs, E);

    k_gemm1<<<(N + 3) / 4, 256, 0, stream>>>(feat, W1, att_s1, att_d1, bufA, a_s1, a_d1, N);
    k_agg1 <<<(N + 3) / 4, 256, 0, stream>>>(deg, offs, srcs, a_s1, a_d1, bufA, b1, bufB, N);
    k_gemm2<<<(N + 3) / 4, 256, 0, stream>>>(bufB, W2, att_s2, att_d2, bufA, a_s2, a_d2, N);
    k_agg2 <<<(N + 3) / 4, 256, 0, stream>>>(deg, offs, srcs, a_s2, a_d2, bufA, b2, label,
                                             out, bins, N);
    k_loss <<<1, 256, 0, stream>>>(bins, out, N);
}

// Round 7
// 565.618 us; speedup vs baseline: 1.3016x; 1.1413x over previous
//
#include <hip/hip_runtime.h>
#include <cstdint>

#define NHEAD 8
#define D1 64      // H1*C1
#define IN_F 128
#define NEG 0.2f
#define NBINS 256  // loss partial-sum bins

// ---------------- Kernel A: h1 = feat @ W1, a_src1/a_dst1 dots ----------------
// Register-tiled: 16 rows/block, wave owns 4 rows. W transposed in LDS with
// stride 129 (bank = (j+k)%32, conflict-free). Per 4 k: 4 ds_read_b32 (Wt) +
// 4 b128 feat broadcasts -> 16 fma. Round-6 lesson: old version issued 2 LDS
// instr per fma -> LDS-pipe bound at 13 TF.
__global__ __launch_bounds__(256) void k_gemm1(
    const float* __restrict__ feat,
    const float* __restrict__ W1,
    const float* __restrict__ att_s,
    const float* __restrict__ att_d,
    float* __restrict__ h1, float* __restrict__ a_src, float* __restrict__ a_dst,
    int N)
{
    __shared__ float Wt[64 * 129];      // Wt[j*129+k] = W1[k*64+j]  (33 KB)
    __shared__ float F[16][IN_F];       // 16 feat rows (8 KB)
    const int tid = threadIdx.x;
    const int base = blockIdx.x * 16;
    for (int i = tid; i < 64 * IN_F; i += 256) {
        int k = i >> 6, j = i & 63;
        Wt[j * 129 + k] = W1[i];        // coalesced global read; LDS banks (j+k)%32
    }
    for (int i = tid; i < 16 * IN_F; i += 256) {
        int r = i >> 7, k = i & 127;
        int n = base + r;
        F[r][k] = (n < N) ? feat[(size_t)n * IN_F + k] : 0.f;
    }
    __syncthreads();
    const int w = tid >> 6, j = tid & 63;
    const float asw = att_s[j], adw = att_d[j];
    const float* wrow = &Wt[j * 129];
    const float* f0 = F[w * 4 + 0];
    const float* f1 = F[w * 4 + 1];
    const float* f2 = F[w * 4 + 2];
    const float* f3 = F[w * 4 + 3];
    float a0 = 0.f, a1 = 0.f, a2 = 0.f, a3 = 0.f;
    #pragma unroll 8
    for (int k = 0; k < IN_F; k += 4) {
        float4 x0 = *(const float4*)&f0[k];
        float4 x1 = *(const float4*)&f1[k];
        float4 x2 = *(const float4*)&f2[k];
        float4 x3 = *(const float4*)&f3[k];
        float w0 = wrow[k], w1 = wrow[k + 1], w2 = wrow[k + 2], w3 = wrow[k + 3];
        a0 = fmaf(x0.x, w0, fmaf(x0.y, w1, fmaf(x0.z, w2, fmaf(x0.w, w3, a0))));
        a1 = fmaf(x1.x, w0, fmaf(x1.y, w1, fmaf(x1.z, w2, fmaf(x1.w, w3, a1))));
        a2 = fmaf(x2.x, w0, fmaf(x2.y, w1, fmaf(x2.z, w2, fmaf(x2.w, w3, a2))));
        a3 = fmaf(x3.x, w0, fmaf(x3.y, w1, fmaf(x3.z, w2, fmaf(x3.w, w3, a3))));
    }
    float acc[4] = {a0, a1, a2, a3};
    #pragma unroll
    for (int r = 0; r < 4; ++r) {
        int n = base + w * 4 + r;
        if (n < N) {
            h1[(size_t)n * D1 + j] = acc[r];
            float ps = acc[r] * asw, pd = acc[r] * adw;
            ps += __shfl_xor(ps, 1); pd += __shfl_xor(pd, 1);
            ps += __shfl_xor(ps, 2); pd += __shfl_xor(pd, 2);
            ps += __shfl_xor(ps, 4); pd += __shfl_xor(pd, 4);
            if ((j & 7) == 0) {
                a_src[n * NHEAD + (j >> 3)] = ps;
                a_dst[n * NHEAD + (j >> 3)] = pd;
            }
        }
    }
}

// ---------------- CSR build: histogram(+rank) / scan / fill ----------------
__global__ __launch_bounds__(256) void k_hist(
    const int* __restrict__ dst, int* __restrict__ deg, int* __restrict__ rank, int E)
{
    int e = blockIdx.x * 256 + threadIdx.x;
    if (e < E) rank[e] = atomicAdd(&deg[dst[e]], 1);   // rank write coalesced
}

__device__ __forceinline__ int block_incl_scan(int v, int tid, int* lds4)
{
    int lane = tid & 63, w = tid >> 6;
    #pragma unroll
    for (int off = 1; off < 64; off <<= 1) {
        int t = __shfl_up(v, off);
        if (lane >= off) v += t;
    }
    if (lane == 63) lds4[w] = v;
    __syncthreads();
    int add = 0;
    #pragma unroll
    for (int i = 0; i < 4; ++i)
        if (i < w) add += lds4[i];
    __syncthreads();
    return v + add;
}

__global__ __launch_bounds__(256) void k_scan1(
    const int* __restrict__ deg, int* __restrict__ locx, int* __restrict__ bsum, int N)
{
    __shared__ int lds4[4];
    int i = blockIdx.x * 256 + threadIdx.x;
    int v = (i < N) ? deg[i] : 0;
    int incl = block_incl_scan(v, threadIdx.x, lds4);
    if (i < N) locx[i] = incl - v;
    if (threadIdx.x == 255) bsum[blockIdx.x] = incl;
}

__global__ __launch_bounds__(256) void k_scan2(int* __restrict__ bsum, int nblk)
{
    __shared__ int lds4[4];
    __shared__ int carry;
    if (threadIdx.x == 0) carry = 0;
    __syncthreads();
    for (int base = 0; base < nblk; base += 256) {
        int i = base + threadIdx.x;
        int v = (i < nblk) ? bsum[i] : 0;
        int incl = block_incl_scan(v, threadIdx.x, lds4);
        int c = carry;
        __syncthreads();
        if (i < nblk) bsum[i] = incl - v + c;   // exclusive offset of block i
        if (threadIdx.x == 255) carry = c + incl;
        __syncthreads();
    }
}

__global__ __launch_bounds__(256) void k_scan3(
    const int* __restrict__ locx, const int* __restrict__ bsum,
    int* __restrict__ offs, int N)
{
    int i = blockIdx.x * 256 + threadIdx.x;
    if (i < N) offs[i] = locx[i] + bsum[i >> 8];
}

// Round-6 lesson: plain scattered 4B stores write through at 64B/op (108 MB
// HBM stream = the whole 126 us). atomicExch executes at L2 -> ~4B/op, line
// stays cached, written back once.
__global__ __launch_bounds__(256) void k_fill(
    const int* __restrict__ src, const int* __restrict__ dst,
    const int* __restrict__ rank, const int* __restrict__ offs,
    int* __restrict__ srcs, int E)
{
    int e = blockIdx.x * 256 + threadIdx.x;
    if (e < E) {
        int p = offs[dst[e]] + rank[e];
        (void)atomicExch(&srcs[p], src[e]);
    }
}

// ---------------- Layer-1 aggregation, dst-grouped, fused norm+bias+ELU ----------------
__global__ __launch_bounds__(256) void k_agg1(
    const int* __restrict__ deg, const int* __restrict__ offs,
    const int* __restrict__ srcs,
    const float* __restrict__ a_s, const float* __restrict__ a_d,
    const float* __restrict__ h1, const float* __restrict__ b1,
    float* __restrict__ x, int N)
{
    const int tid = threadIdx.x, w = tid >> 6, j = tid & 63;
    const int c = j & 7, hh = j >> 3;      // producer: edge-slot c, head hh
    const int n = blockIdx.x * 4 + w;
    if (n >= N) return;
    const int rlen = deg[n], row = offs[n];
    const float ad = a_d[n * NHEAD + hh];
    float acc0 = 0.f, acc1 = 0.f, den = 0.f;
    for (int base = 0; base < rlen; base += 8) {
        int m = rlen - base; if (m > 8) m = 8;
        int myS = 0; float ex = 0.f;
        if (c < m) {
            myS = srcs[row + base + c];
            float v = a_s[myS * NHEAD + hh] + ad;
            v = v > 0.f ? v : NEG * v;
            ex = expf(v);
        }
        float ds = ex;                      // per-head denom: aligned 8-lane group reduce
        ds += __shfl_xor(ds, 1);
        ds += __shfl_xor(ds, 2);
        ds += __shfl_xor(ds, 4);
        den += ds;
        if (m == 8) {
            int   s8[8]; float e8[8], l8[8];
            #pragma unroll
            for (int k = 0; k < 8; ++k) {
                s8[k] = __shfl(myS, k);
                e8[k] = __shfl(ex, (j & 0x38) | k);
            }
            #pragma unroll
            for (int k = 0; k < 8; ++k)
                l8[k] = h1[(size_t)s8[k] * D1 + j];   // 8 loads in flight
            #pragma unroll
            for (int k = 0; k < 8; ++k) {
                if (k & 1) acc1 = fmaf(e8[k], l8[k], acc1);
                else       acc0 = fmaf(e8[k], l8[k], acc0);
            }
        } else {
            for (int k = 0; k < m; ++k) {
                int s = __shfl(myS, k);
                float exk = __shfl(ex, (j & 0x38) | k);
                if (k & 1) acc1 = fmaf(exk, h1[(size_t)s * D1 + j], acc1);
                else       acc0 = fmaf(exk, h1[(size_t)s * D1 + j], acc0);
            }
        }
    }
    float o = (acc0 + acc1) / den + b1[j];
    x[(size_t)n * D1 + j] = o > 0.f ? o : expm1f(o);
}

// ---------------- Kernel D: h2 = x @ W2, a_src2/a_dst2 (register-tiled) ----------------
__global__ __launch_bounds__(256) void k_gemm2(
    const float* __restrict__ x,
    const float* __restrict__ W2,
    const float* __restrict__ att_s,
    const float* __restrict__ att_d,
    float* __restrict__ h2, float* __restrict__ a_src, float* __restrict__ a_dst,
    int N)
{
    __shared__ float Wt[64 * 65];       // Wt[j*65+k] = W2[k*64+j]  (16.6 KB)
    __shared__ float F[16][64];         // 4 KB
    const int tid = threadIdx.x;
    const int base = blockIdx.x * 16;
    for (int i = tid; i < 64 * 64; i += 256) {
        int k = i >> 6, j = i & 63;
        Wt[j * 65 + k] = W2[i];
    }
    for (int i = tid; i < 16 * 64; i += 256) {
        int r = i >> 6, k = i & 63;
        int n = base + r;
        F[r][k] = (n < N) ? x[(size_t)n * 64 + k] : 0.f;
    }
    __syncthreads();
    const int w = tid >> 6, j = tid & 63;
    const float asw = att_s[j], adw = att_d[j];
    const float* wrow = &Wt[j * 65];
    const float* f0 = F[w * 4 + 0];
    const float* f1 = F[w * 4 + 1];
    const float* f2 = F[w * 4 + 2];
    const float* f3 = F[w * 4 + 3];
    float a0 = 0.f, a1 = 0.f, a2 = 0.f, a3 = 0.f;
    #pragma unroll 8
    for (int k = 0; k < 64; k += 4) {
        float4 x0 = *(const float4*)&f0[k];
        float4 x1 = *(const float4*)&f1[k];
        float4 x2 = *(const float4*)&f2[k];
        float4 x3 = *(const float4*)&f3[k];
        float w0 = wrow[k], w1 = wrow[k + 1], w2 = wrow[k + 2], w3 = wrow[k + 3];
        a0 = fmaf(x0.x, w0, fmaf(x0.y, w1, fmaf(x0.z, w2, fmaf(x0.w, w3, a0))));
        a1 = fmaf(x1.x, w0, fmaf(x1.y, w1, fmaf(x1.z, w2, fmaf(x1.w, w3, a1))));
        a2 = fmaf(x2.x, w0, fmaf(x2.y, w1, fmaf(x2.z, w2, fmaf(x2.w, w3, a2))));
        a3 = fmaf(x3.x, w0, fmaf(x3.y, w1, fmaf(x3.z, w2, fmaf(x3.w, w3, a3))));
    }
    float acc[4] = {a0, a1, a2, a3};
    #pragma unroll
    for (int r = 0; r < 4; ++r) {
        int n = base + w * 4 + r;
        if (n < N) {
            h2[(size_t)n * 64 + j] = acc[r];
            float ps = acc[r] * asw, pd = acc[r] * adw;
            #pragma unroll
            for (int off = 1; off < 64; off <<= 1) {
                ps += __shfl_xor(ps, off);
                pd += __shfl_xor(pd, off);
            }
            if (j == 0) { a_src[n] = ps; a_dst[n] = pd; }
        }
    }
}

// ---------------- Layer-2 aggregation + bias + log-softmax + argmax + NLL ----------------
__global__ __launch_bounds__(256) void k_agg2(
    const int* __restrict__ deg, const int* __restrict__ offs,
    const int* __restrict__ srcs,
    const float* __restrict__ a_s, const float* __restrict__ a_d,
    const float* __restrict__ h2, const float* __restrict__ b2,
    const int* __restrict__ label,
    float* __restrict__ dout, double* __restrict__ bins, int N)
{
    __shared__ float snll[4];
    const int tid = threadIdx.x, w = tid >> 6, j = tid & 63;
    const int n = blockIdx.x * 4 + w;
    if (j == 0) snll[w] = 0.f;
    if (n < N) {
        const int rlen = deg[n], row = offs[n];
        const float ad = a_d[n];
        float acc0 = 0.f, acc1 = 0.f, den = 0.f;
        for (int base = 0; base < rlen; base += 64) {
            int m = rlen - base; if (m > 64) m = 64;
            int myS = 0; float ex = 0.f;
            if (j < m) {
                myS = srcs[row + base + j];
                float v = a_s[myS] + ad;
                v = v > 0.f ? v : NEG * v;
                ex = expf(v);
            }
            float ds = ex;
            #pragma unroll
            for (int off = 1; off < 64; off <<= 1) ds += __shfl_xor(ds, off);
            den += ds;
            int k = 0;
            for (; k + 8 <= m; k += 8) {
                int   s8[8]; float e8[8], l8[8];
                #pragma unroll
                for (int i = 0; i < 8; ++i) {
                    s8[i] = __shfl(myS, k + i);
                    e8[i] = __shfl(ex, k + i);
                }
                #pragma unroll
                for (int i = 0; i < 8; ++i)
                    l8[i] = h2[(size_t)s8[i] * 64 + j];   // 8 loads in flight
                #pragma unroll
                for (int i = 0; i < 8; ++i) {
                    if (i & 1) acc1 = fmaf(e8[i], l8[i], acc1);
                    else       acc0 = fmaf(e8[i], l8[i], acc0);
                }
            }
            for (; k < m; ++k) {
                int s = __shfl(myS, k);
                float exk = __shfl(ex, k);
                if (k & 1) acc1 = fmaf(exk, h2[(size_t)s * 64 + j], acc1);
                else       acc0 = fmaf(exk, h2[(size_t)s * 64 + j], acc0);
            }
        }
        float sc = (acc0 + acc1) / den + b2[j];
        // argmax, lowest-index tie-break (np.argmax)
        float mv = sc; int mi = j;
        #pragma unroll
        for (int off = 1; off < 64; off <<= 1) {
            float ov = __shfl_xor(mv, off);
            int oi = __shfl_xor(mi, off);
            if (ov > mv || (ov == mv && oi < mi)) { mv = ov; mi = oi; }
        }
        float se = expf(sc - mv);
        #pragma unroll
        for (int off = 1; off < 64; off <<= 1) se += __shfl_xor(se, off);
        int lab = label[n];
        float sl = __shfl(sc, lab);
        if (j == 0) {
            snll[w] = mv + logf(se) - sl;
            dout[1 + n] = (float)mi;
            dout[1 + (size_t)N + n] = (float)lab;
        }
    }
    __syncthreads();
    if (tid == 0) {
        double bsum = (double)snll[0] + (double)snll[1]
                    + (double)snll[2] + (double)snll[3];
        atomicAdd(&bins[blockIdx.x & (NBINS - 1)], bsum);
    }
}

// Single block of 256: reduce NBINS doubles -> loss
__global__ __launch_bounds__(256) void k_loss(
    const double* __restrict__ bins, float* __restrict__ dout, int N)
{
    __shared__ double sw[4];
    const int tid = threadIdx.x;
    double v = bins[tid];
    #pragma unroll
    for (int off = 1; off < 64; off <<= 1) v += __shfl_xor(v, off);
    if ((tid & 63) == 0) sw[tid >> 6] = v;
    __syncthreads();
    if (tid == 0)
        dout[0] = (float)((sw[0] + sw[1] + sw[2] + sw[3]) / (double)N);
}

extern "C" void kernel_launch(void* const* d_in, const int* in_sizes, int n_in,
                              void* d_out, int out_size, void* d_ws, size_t ws_size,
                              hipStream_t stream)
{
    const float* feat   = (const float*)d_in[1];
    const int*   edge   = (const int*)d_in[2];
    const int*   label  = (const int*)d_in[4];
    const float* W1     = (const float*)d_in[5];
    const float* att_s1 = (const float*)d_in[6];
    const float* att_d1 = (const float*)d_in[7];
    const float* b1     = (const float*)d_in[8];
    const float* W2     = (const float*)d_in[9];
    const float* att_s2 = (const float*)d_in[10];
    const float* att_d2 = (const float*)d_in[11];
    const float* b2     = (const float*)d_in[12];

    const int N = in_sizes[0];
    const int E = in_sizes[2] / 2;
    const int* src = edge;
    const int* dst = edge + E;

    // workspace layout (~66 MB):
    float* bufA = (float*)d_ws;               // N*64: h1, later reused as h2
    float* bufB = bufA + (size_t)N * 64;      // N*64: x (elu output); ALSO aliases rank[E]
    float* a_s1 = bufB + (size_t)N * 64;      // N*8 (layer2 reuses: a_s2=[0..N), a_d2=[N..2N))
    float* a_d1 = a_s1 + (size_t)N * 8;       // N*8
    int*   deg  = (int*)(a_d1 + (size_t)N * 8); // N
    int*   offs = deg + N;                    // N
    int*   srcs = offs + N;                   // E
    int*   locx = srcs + E;                   // N (scan scratch)
    int*   bsum = locx + N;                   // nblk (scan scratch)
    double* bins = (double*)(((uintptr_t)(bsum + ((N + 255) / 256) + 1) + 7) & ~(uintptr_t)7);

    // rank[E] aliases bufB: dead before k_agg1 writes x. E <= N*64 required (1.7M << 6.4M ok).
    int* rank = (int*)bufB;

    float* a_s2 = a_s1;
    float* a_d2 = a_s1 + N;

    float* out = (float*)d_out;

    const int nblk = (N + 255) / 256;
    const int egrid = (E + 255) / 256;

    hipMemsetAsync(deg, 0, (size_t)N * sizeof(int), stream);
    hipMemsetAsync(bins, 0, NBINS * sizeof(double), stream);

    // CSR build (rebuilt every call — no static state)
    k_hist <<<egrid, 256, 0, stream>>>(dst, deg, rank, E);
    k_scan1<<<nblk, 256, 0, stream>>>(deg, locx, bsum, N);
    k_scan2<<<1, 256, 0, stream>>>(bsum, nblk);
    k_scan3<<<nblk, 256, 0, stream>>>(locx, bsum, offs, N);
    k_fill <<<egrid, 256, 0, stream>>>(src, dst, rank, offs, srcs, E);

    k_gemm1<<<(N + 15) / 16, 256, 0, stream>>>(feat, W1, att_s1, att_d1, bufA, a_s1, a_d1, N);
    k_agg1 <<<(N + 3) / 4, 256, 0, stream>>>(deg, offs, srcs, a_s1, a_d1, bufA, b1, bufB, N);
    k_gemm2<<<(N + 15) / 16, 256, 0, stream>>>(bufB, W2, att_s2, att_d2, bufA, a_s2, a_d2, N);
    k_agg2 <<<(N + 3) / 4, 256, 0, stream>>>(deg, offs, srcs, a_s2, a_d2, bufA, b2, label,
                                             out, bins, N);
    k_loss <<<1, 256, 0, stream>>>(bins, out, N);
}

// Round 9
// 531.163 us; speedup vs baseline: 1.3860x; 1.0649x over previous
//
#include <hip/hip_runtime.h>
#include <cstdint>

#define NHEAD 8
#define D1 64      // H1*C1
#define IN_F 128
#define NEG 0.2f
#define NBINS 256  // loss partial-sum bins

// NOTE round-8 lesson: a macro param named `w` captured the `.w` member token.
// Inline function instead.
__device__ __forceinline__ void fma4(float4& a, float s, const float4& v)
{
    a.x = fmaf(s, v.x, a.x); a.y = fmaf(s, v.y, a.y);
    a.z = fmaf(s, v.z, a.z); a.w = fmaf(s, v.w, a.w);
}

// ---------------- Kernel A: h1 = feat @ W1, a_src1/a_dst1 dots ----------------
// 64x64 block tile, 4x4 register tile/thread, K in two 64-halves.
// Round-7 lesson: 4x1 tile = 5 LDS b128 per 16 fma -> LDS-pipe bound.
// 4x4 tile = 8 b128 per 64 fma -> compute-bound. LDS 33.4 KB -> 4 blocks/CU.
__global__ __launch_bounds__(256) void k_gemm1(
    const float* __restrict__ feat,
    const float* __restrict__ W1,
    const float* __restrict__ att_s,
    const float* __restrict__ att_d,
    float* __restrict__ h1, float* __restrict__ a_src, float* __restrict__ a_dst,
    int N)
{
    __shared__ float Wh[64 * 64];   // [kk][c], natural layout, 16 KB
    __shared__ float Fh[64 * 68];   // [r][kk], stride 68 (2-way-free banks), 17.4 KB
    const int tid = threadIdx.x;
    const int tx = tid & 15, ty = tid >> 4;      // col group / row group
    const int base = blockIdx.x * 64;
    float4 acc0 = {0,0,0,0}, acc1 = {0,0,0,0}, acc2 = {0,0,0,0}, acc3 = {0,0,0,0};

    for (int p = 0; p < 2; ++p) {
        if (p) __syncthreads();
        for (int i = tid; i < 64 * 64; i += 256)
            Wh[i] = W1[p * 4096 + i];            // W1[(64p+kk)*64+c]
        for (int i = tid; i < 64 * 64; i += 256) {
            int r = i >> 6, kk = i & 63;
            int n = base + r;
            Fh[r * 68 + kk] = (n < N) ? feat[(size_t)n * IN_F + p * 64 + kk] : 0.f;
        }
        __syncthreads();
        const float* wk = &Wh[4 * tx];
        const float* f0 = &Fh[(4 * ty + 0) * 68];
        const float* f1 = &Fh[(4 * ty + 1) * 68];
        const float* f2 = &Fh[(4 * ty + 2) * 68];
        const float* f3 = &Fh[(4 * ty + 3) * 68];
        #pragma unroll 4
        for (int kk = 0; kk < 64; kk += 4) {
            float4 fa = *(const float4*)&f0[kk];
            float4 fb = *(const float4*)&f1[kk];
            float4 fc = *(const float4*)&f2[kk];
            float4 fd = *(const float4*)&f3[kk];
            float4 w0 = *(const float4*)&wk[(kk + 0) * 64];
            float4 w1 = *(const float4*)&wk[(kk + 1) * 64];
            float4 w2 = *(const float4*)&wk[(kk + 2) * 64];
            float4 w3 = *(const float4*)&wk[(kk + 3) * 64];
            fma4(acc0, fa.x, w0); fma4(acc0, fa.y, w1); fma4(acc0, fa.z, w2); fma4(acc0, fa.w, w3);
            fma4(acc1, fb.x, w0); fma4(acc1, fb.y, w1); fma4(acc1, fb.z, w2); fma4(acc1, fb.w, w3);
            fma4(acc2, fc.x, w0); fma4(acc2, fc.y, w1); fma4(acc2, fc.z, w2); fma4(acc2, fc.w, w3);
            fma4(acc3, fd.x, w0); fma4(acc3, fd.y, w1); fma4(acc3, fd.z, w2); fma4(acc3, fd.w, w3);
        }
    }
    const float4 as4 = *(const float4*)&att_s[4 * tx];
    const float4 ad4 = *(const float4*)&att_d[4 * tx];
    float4 accs[4] = {acc0, acc1, acc2, acc3};
    #pragma unroll
    for (int i = 0; i < 4; ++i) {
        int n = base + 4 * ty + i;
        if (n < N) {
            *(float4*)&h1[(size_t)n * D1 + 4 * tx] = accs[i];
            float ps = accs[i].x * as4.x + accs[i].y * as4.y + accs[i].z * as4.z + accs[i].w * as4.w;
            float pd = accs[i].x * ad4.x + accs[i].y * ad4.y + accs[i].z * ad4.z + accs[i].w * ad4.w;
            ps += __shfl_xor(ps, 1);             // tx pair (2h,2h+1) -> head h sum
            pd += __shfl_xor(pd, 1);
            if ((tx & 1) == 0) {
                a_src[n * NHEAD + (tx >> 1)] = ps;
                a_dst[n * NHEAD + (tx >> 1)] = pd;
            }
        }
    }
}

// ---------------- CSR build: histogram(+rank) / scan / fill ----------------
__global__ __launch_bounds__(256) void k_hist(
    const int* __restrict__ dst, int* __restrict__ deg, int* __restrict__ rank, int E)
{
    int e = blockIdx.x * 256 + threadIdx.x;
    if (e < E) rank[e] = atomicAdd(&deg[dst[e]], 1);   // rank write coalesced
}

__device__ __forceinline__ int block_incl_scan(int v, int tid, int* lds4)
{
    int lane = tid & 63, w = tid >> 6;
    #pragma unroll
    for (int off = 1; off < 64; off <<= 1) {
        int t = __shfl_up(v, off);
        if (lane >= off) v += t;
    }
    if (lane == 63) lds4[w] = v;
    __syncthreads();
    int add = 0;
    #pragma unroll
    for (int i = 0; i < 4; ++i)
        if (i < w) add += lds4[i];
    __syncthreads();
    return v + add;
}

__global__ __launch_bounds__(256) void k_scan1(
    const int* __restrict__ deg, int* __restrict__ locx, int* __restrict__ bsum, int N)
{
    __shared__ int lds4[4];
    int i = blockIdx.x * 256 + threadIdx.x;
    int v = (i < N) ? deg[i] : 0;
    int incl = block_incl_scan(v, threadIdx.x, lds4);
    if (i < N) locx[i] = incl - v;
    if (threadIdx.x == 255) bsum[blockIdx.x] = incl;
}

__global__ __launch_bounds__(256) void k_scan2(int* __restrict__ bsum, int nblk)
{
    __shared__ int lds4[4];
    __shared__ int carry;
    if (threadIdx.x == 0) carry = 0;
    __syncthreads();
    for (int base = 0; base < nblk; base += 256) {
        int i = base + threadIdx.x;
        int v = (i < nblk) ? bsum[i] : 0;
        int incl = block_incl_scan(v, threadIdx.x, lds4);
        int c = carry;
        __syncthreads();
        if (i < nblk) bsum[i] = incl - v + c;   // exclusive offset of block i
        if (threadIdx.x == 255) carry = c + incl;
        __syncthreads();
    }
}

__global__ __launch_bounds__(256) void k_scan3(
    const int* __restrict__ locx, const int* __restrict__ bsum,
    int* __restrict__ offs, int N)
{
    int i = blockIdx.x * 256 + threadIdx.x;
    if (i < N) offs[i] = locx[i] + bsum[i >> 8];
}

// atomicExch: scattered 4B plain stores write through at 64B/op; exch stays in L2.
__global__ __launch_bounds__(256) void k_fill(
    const int* __restrict__ src, const int* __restrict__ dst,
    const int* __restrict__ rank, const int* __restrict__ offs,
    int* __restrict__ srcs, int E)
{
    int e = blockIdx.x * 256 + threadIdx.x;
    if (e < E) {
        int p = offs[dst[e]] + rank[e];
        (void)atomicExch(&srcs[p], src[e]);
    }
}

// ---------------- Layer-1 aggregation, dst-grouped, fused norm+bias+ELU ----------------
// Round-7 lesson: __shfl = ds_bpermute (LDS pipe). Uniform broadcasts use
// v_readlane (SGPR result -> saddr loads); only the head-dependent ex shfl remains.
__global__ __launch_bounds__(256) void k_agg1(
    const int* __restrict__ deg, const int* __restrict__ offs,
    const int* __restrict__ srcs,
    const float* __restrict__ a_s, const float* __restrict__ a_d,
    const float* __restrict__ h1, const float* __restrict__ b1,
    float* __restrict__ x, int N)
{
    const int tid = threadIdx.x, w = tid >> 6, j = tid & 63;
    const int c = j & 7, hh = j >> 3;      // producer: edge-slot c, head hh
    const int n = blockIdx.x * 4 + w;
    if (n >= N) return;
    const int rlen = deg[n], row = offs[n];
    const float ad = a_d[n * NHEAD + hh];
    float acc0 = 0.f, acc1 = 0.f, den = 0.f;
    for (int base = 0; base < rlen; base += 8) {
        int m = rlen - base; if (m > 8) m = 8;
        int myS = 0; float ex = 0.f;
        if (c < m) {
            myS = srcs[row + base + c];
            float v = a_s[myS * NHEAD + hh] + ad;
            v = v > 0.f ? v : NEG * v;
            ex = expf(v);
        }
        float ds = ex;                      // per-head denom: aligned 8-lane group reduce
        ds += __shfl_xor(ds, 1);
        ds += __shfl_xor(ds, 2);
        ds += __shfl_xor(ds, 4);
        den += ds;
        if (m == 8) {
            int   s8[8]; float e8[8], l8[8];
            #pragma unroll
            for (int k = 0; k < 8; ++k) {
                s8[k] = __builtin_amdgcn_readlane(myS, k);     // lane k holds edge k's src
                e8[k] = __shfl(ex, (j & 0x38) | k);            // head-dependent lane
            }
            #pragma unroll
            for (int k = 0; k < 8; ++k)
                l8[k] = h1[(size_t)s8[k] * D1 + j];   // saddr form, 8 in flight
            #pragma unroll
            for (int k = 0; k < 8; ++k) {
                if (k & 1) acc1 = fmaf(e8[k], l8[k], acc1);
                else       acc0 = fmaf(e8[k], l8[k], acc0);
            }
        } else {
            for (int k = 0; k < m; ++k) {
                int s = __shfl(myS, k);
                float exk = __shfl(ex, (j & 0x38) | k);
                if (k & 1) acc1 = fmaf(exk, h1[(size_t)s * D1 + j], acc1);
                else       acc0 = fmaf(exk, h1[(size_t)s * D1 + j], acc0);
            }
        }
    }
    float o = (acc0 + acc1) / den + b1[j];
    x[(size_t)n * D1 + j] = o > 0.f ? o : expm1f(o);
}

// ---------------- Kernel D: h2 = x @ W2, a_src2/a_dst2 (4x4 register tile) ----------------
__global__ __launch_bounds__(256) void k_gemm2(
    const float* __restrict__ x,
    const float* __restrict__ W2,
    const float* __restrict__ att_s,
    const float* __restrict__ att_d,
    float* __restrict__ h2, float* __restrict__ a_src, float* __restrict__ a_dst,
    int N)
{
    __shared__ float Wh[64 * 64];   // [kk][c], 16 KB
    __shared__ float Fh[64 * 68];   // [r][kk], 17.4 KB
    const int tid = threadIdx.x;
    const int tx = tid & 15, ty = tid >> 4;
    const int base = blockIdx.x * 64;
    for (int i = tid; i < 64 * 64; i += 256)
        Wh[i] = W2[i];
    for (int i = tid; i < 64 * 64; i += 256) {
        int r = i >> 6, kk = i & 63;
        int n = base + r;
        Fh[r * 68 + kk] = (n < N) ? x[(size_t)n * 64 + kk] : 0.f;
    }
    __syncthreads();
    float4 acc0 = {0,0,0,0}, acc1 = {0,0,0,0}, acc2 = {0,0,0,0}, acc3 = {0,0,0,0};
    const float* wk = &Wh[4 * tx];
    const float* f0 = &Fh[(4 * ty + 0) * 68];
    const float* f1 = &Fh[(4 * ty + 1) * 68];
    const float* f2 = &Fh[(4 * ty + 2) * 68];
    const float* f3 = &Fh[(4 * ty + 3) * 68];
    #pragma unroll 4
    for (int kk = 0; kk < 64; kk += 4) {
        float4 fa = *(const float4*)&f0[kk];
        float4 fb = *(const float4*)&f1[kk];
        float4 fc = *(const float4*)&f2[kk];
        float4 fd = *(const float4*)&f3[kk];
        float4 w0 = *(const float4*)&wk[(kk + 0) * 64];
        float4 w1 = *(const float4*)&wk[(kk + 1) * 64];
        float4 w2 = *(const float4*)&wk[(kk + 2) * 64];
        float4 w3 = *(const float4*)&wk[(kk + 3) * 64];
        fma4(acc0, fa.x, w0); fma4(acc0, fa.y, w1); fma4(acc0, fa.z, w2); fma4(acc0, fa.w, w3);
        fma4(acc1, fb.x, w0); fma4(acc1, fb.y, w1); fma4(acc1, fb.z, w2); fma4(acc1, fb.w, w3);
        fma4(acc2, fc.x, w0); fma4(acc2, fc.y, w1); fma4(acc2, fc.z, w2); fma4(acc2, fc.w, w3);
        fma4(acc3, fd.x, w0); fma4(acc3, fd.y, w1); fma4(acc3, fd.z, w2); fma4(acc3, fd.w, w3);
    }
    const float4 as4 = *(const float4*)&att_s[4 * tx];
    const float4 ad4 = *(const float4*)&att_d[4 * tx];
    float4 accs[4] = {acc0, acc1, acc2, acc3};
    #pragma unroll
    for (int i = 0; i < 4; ++i) {
        int n = base + 4 * ty + i;
        if (n < N) {
            *(float4*)&h2[(size_t)n * 64 + 4 * tx] = accs[i];
            float ps = accs[i].x * as4.x + accs[i].y * as4.y + accs[i].z * as4.z + accs[i].w * as4.w;
            float pd = accs[i].x * ad4.x + accs[i].y * ad4.y + accs[i].z * ad4.z + accs[i].w * ad4.w;
            ps += __shfl_xor(ps, 1); pd += __shfl_xor(pd, 1);
            ps += __shfl_xor(ps, 2); pd += __shfl_xor(pd, 2);
            ps += __shfl_xor(ps, 4); pd += __shfl_xor(pd, 4);
            ps += __shfl_xor(ps, 8); pd += __shfl_xor(pd, 8);
            if (tx == 0) { a_src[n] = ps; a_dst[n] = pd; }
        }
    }
}

// ---------------- Layer-2 aggregation + bias + log-softmax + argmax + NLL ----------------
// All broadcasts wave-uniform -> readlane (no bpermute in the hot loop).
__global__ __launch_bounds__(256) void k_agg2(
    const int* __restrict__ deg, const int* __restrict__ offs,
    const int* __restrict__ srcs,
    const float* __restrict__ a_s, const float* __restrict__ a_d,
    const float* __restrict__ h2, const float* __restrict__ b2,
    const int* __restrict__ label,
    float* __restrict__ dout, double* __restrict__ bins, int N)
{
    __shared__ float snll[4];
    const int tid = threadIdx.x, w = tid >> 6, j = tid & 63;
    const int n = blockIdx.x * 4 + w;
    if (j == 0) snll[w] = 0.f;
    if (n < N) {
        const int rlen = deg[n], row = offs[n];
        const float ad = a_d[n];
        float acc0 = 0.f, acc1 = 0.f, den = 0.f;
        for (int base = 0; base < rlen; base += 64) {
            int m = rlen - base; if (m > 64) m = 64;
            int myS = 0; float ex = 0.f;
            if (j < m) {
                myS = srcs[row + base + j];
                float v = a_s[myS] + ad;
                v = v > 0.f ? v : NEG * v;
                ex = expf(v);
            }
            float ds = ex;
            #pragma unroll
            for (int off = 1; off < 64; off <<= 1) ds += __shfl_xor(ds, off);
            den += ds;
            int k = 0;
            for (; k + 8 <= m; k += 8) {
                int   s8[8]; float e8[8], l8[8];
                #pragma unroll
                for (int i = 0; i < 8; ++i) {
                    s8[i] = __builtin_amdgcn_readlane(myS, k + i);
                    e8[i] = __int_as_float(__builtin_amdgcn_readlane(__float_as_int(ex), k + i));
                }
                #pragma unroll
                for (int i = 0; i < 8; ++i)
                    l8[i] = h2[(size_t)s8[i] * 64 + j];   // saddr form, 8 in flight
                #pragma unroll
                for (int i = 0; i < 8; ++i) {
                    if (i & 1) acc1 = fmaf(e8[i], l8[i], acc1);
                    else       acc0 = fmaf(e8[i], l8[i], acc0);
                }
            }
            for (; k < m; ++k) {
                int s = __shfl(myS, k);
                float exk = __shfl(ex, k);
                if (k & 1) acc1 = fmaf(exk, h2[(size_t)s * 64 + j], acc1);
                else       acc0 = fmaf(exk, h2[(size_t)s * 64 + j], acc0);
            }
        }
        float sc = (acc0 + acc1) / den + b2[j];
        // argmax, lowest-index tie-break (np.argmax)
        float mv = sc; int mi = j;
        #pragma unroll
        for (int off = 1; off < 64; off <<= 1) {
            float ov = __shfl_xor(mv, off);
            int oi = __shfl_xor(mi, off);
            if (ov > mv || (ov == mv && oi < mi)) { mv = ov; mi = oi; }
        }
        float se = expf(sc - mv);
        #pragma unroll
        for (int off = 1; off < 64; off <<= 1) se += __shfl_xor(se, off);
        int lab = label[n];
        float sl = __shfl(sc, lab);
        if (j == 0) {
            snll[w] = mv + logf(se) - sl;
            dout[1 + n] = (float)mi;
            dout[1 + (size_t)N + n] = (float)lab;
        }
    }
    __syncthreads();
    if (tid == 0) {
        double bsum = (double)snll[0] + (double)snll[1]
                    + (double)snll[2] + (double)snll[3];
        atomicAdd(&bins[blockIdx.x & (NBINS - 1)], bsum);
    }
}

// Single block of 256: reduce NBINS doubles -> loss
__global__ __launch_bounds__(256) void k_loss(
    const double* __restrict__ bins, float* __restrict__ dout, int N)
{
    __shared__ double sw[4];
    const int tid = threadIdx.x;
    double v = bins[tid];
    #pragma unroll
    for (int off = 1; off < 64; off <<= 1) v += __shfl_xor(v, off);
    if ((tid & 63) == 0) sw[tid >> 6] = v;
    __syncthreads();
    if (tid == 0)
        dout[0] = (float)((sw[0] + sw[1] + sw[2] + sw[3]) / (double)N);
}

extern "C" void kernel_launch(void* const* d_in, const int* in_sizes, int n_in,
                              void* d_out, int out_size, void* d_ws, size_t ws_size,
                              hipStream_t stream)
{
    const float* feat   = (const float*)d_in[1];
    const int*   edge   = (const int*)d_in[2];
    const int*   label  = (const int*)d_in[4];
    const float* W1     = (const float*)d_in[5];
    const float* att_s1 = (const float*)d_in[6];
    const float* att_d1 = (const float*)d_in[7];
    const float* b1     = (const float*)d_in[8];
    const float* W2     = (const float*)d_in[9];
    const float* att_s2 = (const float*)d_in[10];
    const float* att_d2 = (const float*)d_in[11];
    const float* b2     = (const float*)d_in[12];

    const int N = in_sizes[0];
    const int E = in_sizes[2] / 2;
    const int* src = edge;
    const int* dst = edge + E;

    // workspace layout (~66 MB):
    float* bufA = (float*)d_ws;               // N*64: h1, later reused as h2
    float* bufB = bufA + (size_t)N * 64;      // N*64: x (elu output); ALSO aliases rank[E]
    float* a_s1 = bufB + (size_t)N * 64;      // N*8 (layer2 reuses: a_s2=[0..N), a_d2=[N..2N))
    float* a_d1 = a_s1 + (size_t)N * 8;       // N*8
    int*   deg  = (int*)(a_d1 + (size_t)N * 8); // N
    int*   offs = deg + N;                    // N
    int*   srcs = offs + N;                   // E
    int*   locx = srcs + E;                   // N (scan scratch)
    int*   bsum = locx + N;                   // nblk (scan scratch)
    double* bins = (double*)(((uintptr_t)(bsum + ((N + 255) / 256) + 1) + 7) & ~(uintptr_t)7);

    // rank[E] aliases bufB: dead before k_agg1 writes x. E <= N*64 required (1.7M << 6.4M ok).
    int* rank = (int*)bufB;

    float* a_s2 = a_s1;
    float* a_d2 = a_s1 + N;

    float* out = (float*)d_out;

    const int nblk = (N + 255) / 256;
    const int egrid = (E + 255) / 256;

    hipMemsetAsync(deg, 0, (size_t)N * sizeof(int), stream);
    hipMemsetAsync(bins, 0, NBINS * sizeof(double), stream);

    // CSR build (rebuilt every call — no static state)
    k_hist <<<egrid, 256, 0, stream>>>(dst, deg, rank, E);
    k_scan1<<<nblk, 256, 0, stream>>>(deg, locx, bsum, N);
    k_scan2<<<1, 256, 0, stream>>>(bsum, nblk);
    k_scan3<<<nblk, 256, 0, stream>>>(locx, bsum, offs, N);
    k_fill <<<egrid, 256, 0, stream>>>(src, dst, rank, offs, srcs, E);

    k_gemm1<<<(N + 63) / 64, 256, 0, stream>>>(feat, W1, att_s1, att_d1, bufA, a_s1, a_d1, N);
    k_agg1 <<<(N + 3) / 4, 256, 0, stream>>>(deg, offs, srcs, a_s1, a_d1, bufA, b1, bufB, N);
    k_gemm2<<<(N + 63) / 64, 256, 0, stream>>>(bufB, W2, att_s2, att_d2, bufA, a_s2, a_d2, N);
    k_agg2 <<<(N + 3) / 4, 256, 0, stream>>>(deg, offs, srcs, a_s2, a_d2, bufA, b2, label,
                                             out, bins, N);
    k_loss <<<1, 256, 0, stream>>>(bins, out, N);
}

// Round 10
// 526.375 us; speedup vs baseline: 1.3986x; 1.0091x over previous
//
#include <hip/hip_runtime.h>
#include <cstdint>

#define NHEAD 8
#define D1 64      // H1*C1
#define IN_F 128
#define NEG 0.2f
#define NBINS 256  // loss partial-sum bins

__device__ __forceinline__ void fma4(float4& a, float s, const float4& v)
{
    a.x = fmaf(s, v.x, a.x); a.y = fmaf(s, v.y, a.y);
    a.z = fmaf(s, v.z, a.z); a.w = fmaf(s, v.w, a.w);
}

// ---------------- Kernel A: h1 = feat @ W1, a_src1/a_dst1 dots ----------------
// 64x64 block tile, 4x4 register tile/thread, K in two 64-halves.
__global__ __launch_bounds__(256) void k_gemm1(
    const float* __restrict__ feat,
    const float* __restrict__ W1,
    const float* __restrict__ att_s,
    const float* __restrict__ att_d,
    float* __restrict__ h1, float* __restrict__ a_src, float* __restrict__ a_dst,
    int N)
{
    __shared__ float Wh[64 * 64];   // [kk][c], natural layout, 16 KB
    __shared__ float Fh[64 * 68];   // [r][kk], stride 68, 17.4 KB
    const int tid = threadIdx.x;
    const int tx = tid & 15, ty = tid >> 4;      // col group / row group
    const int base = blockIdx.x * 64;
    float4 acc0 = {0,0,0,0}, acc1 = {0,0,0,0}, acc2 = {0,0,0,0}, acc3 = {0,0,0,0};

    for (int p = 0; p < 2; ++p) {
        if (p) __syncthreads();
        for (int i = tid; i < 64 * 64; i += 256)
            Wh[i] = W1[p * 4096 + i];            // W1[(64p+kk)*64+c]
        for (int i = tid; i < 64 * 64; i += 256) {
            int r = i >> 6, kk = i & 63;
            int n = base + r;
            Fh[r * 68 + kk] = (n < N) ? feat[(size_t)n * IN_F + p * 64 + kk] : 0.f;
        }
        __syncthreads();
        const float* wk = &Wh[4 * tx];
        const float* f0 = &Fh[(4 * ty + 0) * 68];
        const float* f1 = &Fh[(4 * ty + 1) * 68];
        const float* f2 = &Fh[(4 * ty + 2) * 68];
        const float* f3 = &Fh[(4 * ty + 3) * 68];
        #pragma unroll 4
        for (int kk = 0; kk < 64; kk += 4) {
            float4 fa = *(const float4*)&f0[kk];
            float4 fb = *(const float4*)&f1[kk];
            float4 fc = *(const float4*)&f2[kk];
            float4 fd = *(const float4*)&f3[kk];
            float4 w0 = *(const float4*)&wk[(kk + 0) * 64];
            float4 w1 = *(const float4*)&wk[(kk + 1) * 64];
            float4 w2 = *(const float4*)&wk[(kk + 2) * 64];
            float4 w3 = *(const float4*)&wk[(kk + 3) * 64];
            fma4(acc0, fa.x, w0); fma4(acc0, fa.y, w1); fma4(acc0, fa.z, w2); fma4(acc0, fa.w, w3);
            fma4(acc1, fb.x, w0); fma4(acc1, fb.y, w1); fma4(acc1, fb.z, w2); fma4(acc1, fb.w, w3);
            fma4(acc2, fc.x, w0); fma4(acc2, fc.y, w1); fma4(acc2, fc.z, w2); fma4(acc2, fc.w, w3);
            fma4(acc3, fd.x, w0); fma4(acc3, fd.y, w1); fma4(acc3, fd.z, w2); fma4(acc3, fd.w, w3);
        }
    }
    const float4 as4 = *(const float4*)&att_s[4 * tx];
    const float4 ad4 = *(const float4*)&att_d[4 * tx];
    float4 accs[4] = {acc0, acc1, acc2, acc3};
    #pragma unroll
    for (int i = 0; i < 4; ++i) {
        int n = base + 4 * ty + i;
        if (n < N) {
            *(float4*)&h1[(size_t)n * D1 + 4 * tx] = accs[i];
            float ps = accs[i].x * as4.x + accs[i].y * as4.y + accs[i].z * as4.z + accs[i].w * as4.w;
            float pd = accs[i].x * ad4.x + accs[i].y * ad4.y + accs[i].z * ad4.z + accs[i].w * ad4.w;
            ps += __shfl_xor(ps, 1);             // tx pair (2h,2h+1) -> head h sum
            pd += __shfl_xor(pd, 1);
            if ((tx & 1) == 0) {
                a_src[n * NHEAD + (tx >> 1)] = ps;
                a_dst[n * NHEAD + (tx >> 1)] = pd;
            }
        }
    }
}

// ---------------- CSR build: histogram(+rank) / scan / fill ----------------
__global__ __launch_bounds__(256) void k_hist(
    const int* __restrict__ dst, int* __restrict__ deg, int* __restrict__ rank, int E)
{
    int e = blockIdx.x * 256 + threadIdx.x;
    if (e < E) rank[e] = atomicAdd(&deg[dst[e]], 1);
}

__device__ __forceinline__ int block_incl_scan(int v, int tid, int* lds4)
{
    int lane = tid & 63, w = tid >> 6;
    #pragma unroll
    for (int off = 1; off < 64; off <<= 1) {
        int t = __shfl_up(v, off);
        if (lane >= off) v += t;
    }
    if (lane == 63) lds4[w] = v;
    __syncthreads();
    int add = 0;
    #pragma unroll
    for (int i = 0; i < 4; ++i)
        if (i < w) add += lds4[i];
    __syncthreads();
    return v + add;
}

__global__ __launch_bounds__(256) void k_scan1(
    const int* __restrict__ deg, int* __restrict__ locx, int* __restrict__ bsum, int N)
{
    __shared__ int lds4[4];
    int i = blockIdx.x * 256 + threadIdx.x;
    int v = (i < N) ? deg[i] : 0;
    int incl = block_incl_scan(v, threadIdx.x, lds4);
    if (i < N) locx[i] = incl - v;
    if (threadIdx.x == 255) bsum[blockIdx.x] = incl;
}

__global__ __launch_bounds__(256) void k_scan2(int* __restrict__ bsum, int nblk)
{
    __shared__ int lds4[4];
    __shared__ int carry;
    if (threadIdx.x == 0) carry = 0;
    __syncthreads();
    for (int base = 0; base < nblk; base += 256) {
        int i = base + threadIdx.x;
        int v = (i < nblk) ? bsum[i] : 0;
        int incl = block_incl_scan(v, threadIdx.x, lds4);
        int c = carry;
        __syncthreads();
        if (i < nblk) bsum[i] = incl - v + c;
        if (threadIdx.x == 255) carry = c + incl;
        __syncthreads();
    }
}

__global__ __launch_bounds__(256) void k_scan3(
    const int* __restrict__ locx, const int* __restrict__ bsum,
    int* __restrict__ offs, int N)
{
    int i = blockIdx.x * 256 + threadIdx.x;
    if (i < N) offs[i] = locx[i] + bsum[i >> 8];
}

// atomicExch: plain scattered 4B stores write through at 64B/op; exch stays in L2.
__global__ __launch_bounds__(256) void k_fill(
    const int* __restrict__ src, const int* __restrict__ dst,
    const int* __restrict__ rank, const int* __restrict__ offs,
    int* __restrict__ srcs, int E)
{
    int e = blockIdx.x * 256 + threadIdx.x;
    if (e < E) {
        int p = offs[dst[e]] + rank[e];
        (void)atomicExch(&srcs[p], src[e]);
    }
}

// ---------------- Layer-1 aggregation, dst-grouped, fused norm+bias+ELU ----------------
// Round-9 restructure: consumer lane j=(q,t) owns float4 channels 4t..4t+3 (head t>>1),
// edge subset e==q mod 4. One VMEM gathers 4 rows (16 lanes x 16B each):
// per 8-edge chunk 2 VMEM + 4 bpermute (was 8+8). Cross-quad reduce in epilogue.
__global__ __launch_bounds__(256) void k_agg1(
    const int* __restrict__ deg, const int* __restrict__ offs,
    const int* __restrict__ srcs,
    const float* __restrict__ a_s, const float* __restrict__ a_d,
    const float* __restrict__ h1, const float* __restrict__ b1,
    float* __restrict__ x, int N)
{
    const int tid = threadIdx.x, w = tid >> 6, j = tid & 63;
    const int c = j & 7, hh = j >> 3;        // producer: edge-slot c, head hh
    const int t = j & 15, q = j >> 4;        // consumer: channels 4t..4t+3, quad q
    const int exbase = (t >> 1) << 3;        // producer lane base for head t>>1
    const int n = blockIdx.x * 4 + w;
    if (n >= N) return;
    const int rlen = deg[n], row = offs[n];
    const float ad = a_d[n * NHEAD + hh];
    float4 acc = {0.f, 0.f, 0.f, 0.f};
    float den = 0.f;
    int m0 = rlen < 8 ? rlen : 8;
    int myS = (c < m0) ? srcs[row + c] : 0;          // chunk-0 srcs
    for (int base = 0; base < rlen; base += 8) {
        int m = rlen - base; if (m > 8) m = 8;
        int mn = rlen - base - 8; if (mn > 8) mn = 8;
        int myS_n = (c < mn) ? srcs[row + base + 8 + c] : 0;   // prefetch next chunk
        float ex = 0.f;
        if (c < m) {
            float v = a_s[myS * NHEAD + hh] + ad;
            v = v > 0.f ? v : NEG * v;
            ex = expf(v);
        }
        float ds = ex;                      // per-head denom: aligned 8-lane group reduce
        ds += __shfl_xor(ds, 1);
        ds += __shfl_xor(ds, 2);
        ds += __shfl_xor(ds, 4);
        den += ds;
        if (m == 8) {
            int   s0 = __shfl(myS, q);
            int   s1 = __shfl(myS, 4 + q);
            float e0 = __shfl(ex, exbase | q);
            float e1 = __shfl(ex, exbase | (4 + q));
            float4 l0 = *(const float4*)&h1[(size_t)s0 * D1 + 4 * t];
            float4 l1 = *(const float4*)&h1[(size_t)s1 * D1 + 4 * t];
            fma4(acc, e0, l0);
            fma4(acc, e1, l1);
        } else {
            for (int k = 0; k < m; ++k) {
                int   sk = __shfl(myS, k);
                float ek = __shfl(ex, exbase | k);
                if (q == (k & 3)) {
                    float4 lk = *(const float4*)&h1[(size_t)sk * D1 + 4 * t];
                    fma4(acc, ek, lk);
                }
            }
        }
        myS = myS_n;
    }
    // reduce edge-subsets across quads (lanes xor 16, 32)
    acc.x += __shfl_xor(acc.x, 16); acc.y += __shfl_xor(acc.y, 16);
    acc.z += __shfl_xor(acc.z, 16); acc.w += __shfl_xor(acc.w, 16);
    acc.x += __shfl_xor(acc.x, 32); acc.y += __shfl_xor(acc.y, 32);
    acc.z += __shfl_xor(acc.z, 32); acc.w += __shfl_xor(acc.w, 32);
    float denf = __shfl(den, exbase);        // den of head t>>1
    if (q == 0) {
        float4 b = *(const float4*)&b1[4 * t];
        float4 o;
        o.x = acc.x / denf + b.x; o.y = acc.y / denf + b.y;
        o.z = acc.z / denf + b.z; o.w = acc.w / denf + b.w;
        o.x = o.x > 0.f ? o.x : expm1f(o.x);
        o.y = o.y > 0.f ? o.y : expm1f(o.y);
        o.z = o.z > 0.f ? o.z : expm1f(o.z);
        o.w = o.w > 0.f ? o.w : expm1f(o.w);
        *(float4*)&x[(size_t)n * D1 + 4 * t] = o;
    }
}

// ---------------- Kernel D: h2 = x @ W2, a_src2/a_dst2 (4x4 register tile) ----------------
__global__ __launch_bounds__(256) void k_gemm2(
    const float* __restrict__ x,
    const float* __restrict__ W2,
    const float* __restrict__ att_s,
    const float* __restrict__ att_d,
    float* __restrict__ h2, float* __restrict__ a_src, float* __restrict__ a_dst,
    int N)
{
    __shared__ float Wh[64 * 64];
    __shared__ float Fh[64 * 68];
    const int tid = threadIdx.x;
    const int tx = tid & 15, ty = tid >> 4;
    const int base = blockIdx.x * 64;
    for (int i = tid; i < 64 * 64; i += 256)
        Wh[i] = W2[i];
    for (int i = tid; i < 64 * 64; i += 256) {
        int r = i >> 6, kk = i & 63;
        int n = base + r;
        Fh[r * 68 + kk] = (n < N) ? x[(size_t)n * 64 + kk] : 0.f;
    }
    __syncthreads();
    float4 acc0 = {0,0,0,0}, acc1 = {0,0,0,0}, acc2 = {0,0,0,0}, acc3 = {0,0,0,0};
    const float* wk = &Wh[4 * tx];
    const float* f0 = &Fh[(4 * ty + 0) * 68];
    const float* f1 = &Fh[(4 * ty + 1) * 68];
    const float* f2 = &Fh[(4 * ty + 2) * 68];
    const float* f3 = &Fh[(4 * ty + 3) * 68];
    #pragma unroll 4
    for (int kk = 0; kk < 64; kk += 4) {
        float4 fa = *(const float4*)&f0[kk];
        float4 fb = *(const float4*)&f1[kk];
        float4 fc = *(const float4*)&f2[kk];
        float4 fd = *(const float4*)&f3[kk];
        float4 w0 = *(const float4*)&wk[(kk + 0) * 64];
        float4 w1 = *(const float4*)&wk[(kk + 1) * 64];
        float4 w2 = *(const float4*)&wk[(kk + 2) * 64];
        float4 w3 = *(const float4*)&wk[(kk + 3) * 64];
        fma4(acc0, fa.x, w0); fma4(acc0, fa.y, w1); fma4(acc0, fa.z, w2); fma4(acc0, fa.w, w3);
        fma4(acc1, fb.x, w0); fma4(acc1, fb.y, w1); fma4(acc1, fb.z, w2); fma4(acc1, fb.w, w3);
        fma4(acc2, fc.x, w0); fma4(acc2, fc.y, w1); fma4(acc2, fc.z, w2); fma4(acc2, fc.w, w3);
        fma4(acc3, fd.x, w0); fma4(acc3, fd.y, w1); fma4(acc3, fd.z, w2); fma4(acc3, fd.w, w3);
    }
    const float4 as4 = *(const float4*)&att_s[4 * tx];
    const float4 ad4 = *(const float4*)&att_d[4 * tx];
    float4 accs[4] = {acc0, acc1, acc2, acc3};
    #pragma unroll
    for (int i = 0; i < 4; ++i) {
        int n = base + 4 * ty + i;
        if (n < N) {
            *(float4*)&h2[(size_t)n * 64 + 4 * tx] = accs[i];
            float ps = accs[i].x * as4.x + accs[i].y * as4.y + accs[i].z * as4.z + accs[i].w * as4.w;
            float pd = accs[i].x * ad4.x + accs[i].y * ad4.y + accs[i].z * ad4.z + accs[i].w * ad4.w;
            ps += __shfl_xor(ps, 1); pd += __shfl_xor(pd, 1);
            ps += __shfl_xor(ps, 2); pd += __shfl_xor(pd, 2);
            ps += __shfl_xor(ps, 4); pd += __shfl_xor(pd, 4);
            ps += __shfl_xor(ps, 8); pd += __shfl_xor(pd, 8);
            if (tx == 0) { a_src[n] = ps; a_dst[n] = pd; }
        }
    }
}

// ---------------- Layer-2 aggregation + bias + log-softmax + argmax + NLL ----------------
// float4 consumer (channels 4t..4t+3, edge subset q mod 4), 16-edge unrolled groups
// -> 4 row-gathers in flight. Softmax/argmax over the float4 layout: per-lane 4-way,
// then 16-lane quad reduce.
__global__ __launch_bounds__(256) void k_agg2(
    const int* __restrict__ deg, const int* __restrict__ offs,
    const int* __restrict__ srcs,
    const float* __restrict__ a_s, const float* __restrict__ a_d,
    const float* __restrict__ h2, const float* __restrict__ b2,
    const int* __restrict__ label,
    float* __restrict__ dout, double* __restrict__ bins, int N)
{
    __shared__ float snll[4];
    const int tid = threadIdx.x, w = tid >> 6, j = tid & 63;
    const int t = j & 15, q = j >> 4;
    const int n = blockIdx.x * 4 + w;
    if (j == 0) snll[w] = 0.f;
    if (n < N) {
        const int rlen = deg[n], row = offs[n];
        const float ad = a_d[n];
        float4 acc = {0.f, 0.f, 0.f, 0.f};
        float den = 0.f;
        for (int base = 0; base < rlen; base += 64) {
            int m = rlen - base; if (m > 64) m = 64;
            int myS = 0; float ex = 0.f;
            if (j < m) {
                myS = srcs[row + base + j];
                float v = a_s[myS] + ad;
                v = v > 0.f ? v : NEG * v;
                ex = expf(v);
            }
            float ds = ex;
            #pragma unroll
            for (int off = 1; off < 64; off <<= 1) ds += __shfl_xor(ds, off);
            den += ds;
            int eb = 0;
            for (; eb + 16 <= m; eb += 16) {           // 4 gathers in flight
                int s4[4]; float e4[4]; float4 l4[4];
                #pragma unroll
                for (int ii = 0; ii < 4; ++ii) {
                    int e = eb + 4 * ii + q;
                    s4[ii] = __shfl(myS, e);
                    e4[ii] = __shfl(ex, e);
                }
                #pragma unroll
                for (int ii = 0; ii < 4; ++ii)
                    l4[ii] = *(const float4*)&h2[(size_t)s4[ii] * 64 + 4 * t];
                #pragma unroll
                for (int ii = 0; ii < 4; ++ii)
                    fma4(acc, e4[ii], l4[ii]);
            }
            for (; eb + 4 <= m; eb += 4) {
                int e = eb + q;
                int sk = __shfl(myS, e);
                float ek = __shfl(ex, e);
                float4 lk = *(const float4*)&h2[(size_t)sk * 64 + 4 * t];
                fma4(acc, ek, lk);
            }
            for (int k = eb; k < m; ++k) {
                int sk = __shfl(myS, k);
                float ek = __shfl(ex, k);
                if (q == (k & 3)) {
                    float4 lk = *(const float4*)&h2[(size_t)sk * 64 + 4 * t];
                    fma4(acc, ek, lk);
                }
            }
        }
        // reduce edge-subsets across quads
        acc.x += __shfl_xor(acc.x, 16); acc.y += __shfl_xor(acc.y, 16);
        acc.z += __shfl_xor(acc.z, 16); acc.w += __shfl_xor(acc.w, 16);
        acc.x += __shfl_xor(acc.x, 32); acc.y += __shfl_xor(acc.y, 32);
        acc.z += __shfl_xor(acc.z, 32); acc.w += __shfl_xor(acc.w, 32);
        float4 b = *(const float4*)&b2[4 * t];
        float4 sc;
        sc.x = acc.x / den + b.x; sc.y = acc.y / den + b.y;
        sc.z = acc.z / den + b.z; sc.w = acc.w / den + b.w;
        // argmax (lowest-index tie-break): per-lane over 4, then 16-lane quad reduce
        float mv = sc.x; int mi = 4 * t;
        if (sc.y > mv) { mv = sc.y; mi = 4 * t + 1; }
        if (sc.z > mv) { mv = sc.z; mi = 4 * t + 2; }
        if (sc.w > mv) { mv = sc.w; mi = 4 * t + 3; }
        #pragma unroll
        for (int off = 1; off < 16; off <<= 1) {
            float ov = __shfl_xor(mv, off);
            int oi = __shfl_xor(mi, off);
            if (ov > mv || (ov == mv && oi < mi)) { mv = ov; mi = oi; }
        }
        float se = expf(sc.x - mv) + expf(sc.y - mv) + expf(sc.z - mv) + expf(sc.w - mv);
        #pragma unroll
        for (int off = 1; off < 16; off <<= 1) se += __shfl_xor(se, off);
        int lab = label[n];
        int comp = lab & 3;
        float cl = comp == 0 ? sc.x : comp == 1 ? sc.y : comp == 2 ? sc.z : sc.w;
        float sl = __shfl(cl, (j & 0x30) | (lab >> 2));   // same quad, lane t=lab>>2
        if (j == 0) {
            snll[w] = mv + logf(se) - sl;
            dout[1 + n] = (float)mi;
            dout[1 + (size_t)N + n] = (float)lab;
        }
    }
    __syncthreads();
    if (tid == 0) {
        double bsum = (double)snll[0] + (double)snll[1]
                    + (double)snll[2] + (double)snll[3];
        atomicAdd(&bins[blockIdx.x & (NBINS - 1)], bsum);
    }
}

// Single block of 256: reduce NBINS doubles -> loss
__global__ __launch_bounds__(256) void k_loss(
    const double* __restrict__ bins, float* __restrict__ dout, int N)
{
    __shared__ double sw[4];
    const int tid = threadIdx.x;
    double v = bins[tid];
    #pragma unroll
    for (int off = 1; off < 64; off <<= 1) v += __shfl_xor(v, off);
    if ((tid & 63) == 0) sw[tid >> 6] = v;
    __syncthreads();
    if (tid == 0)
        dout[0] = (float)((sw[0] + sw[1] + sw[2] + sw[3]) / (double)N);
}

extern "C" void kernel_launch(void* const* d_in, const int* in_sizes, int n_in,
                              void* d_out, int out_size, void* d_ws, size_t ws_size,
                              hipStream_t stream)
{
    const float* feat   = (const float*)d_in[1];
    const int*   edge   = (const int*)d_in[2];
    const int*   label  = (const int*)d_in[4];
    const float* W1     = (const float*)d_in[5];
    const float* att_s1 = (const float*)d_in[6];
    const float* att_d1 = (const float*)d_in[7];
    const float* b1     = (const float*)d_in[8];
    const float* W2     = (const float*)d_in[9];
    const float* att_s2 = (const float*)d_in[10];
    const float* att_d2 = (const float*)d_in[11];
    const float* b2     = (const float*)d_in[12];

    const int N = in_sizes[0];
    const int E = in_sizes[2] / 2;
    const int* src = edge;
    const int* dst = edge + E;

    // workspace layout (~66 MB):
    float* bufA = (float*)d_ws;               // N*64: h1, later reused as h2
    float* bufB = bufA + (size_t)N * 64;      // N*64: x (elu output); ALSO aliases rank[E]
    float* a_s1 = bufB + (size_t)N * 64;      // N*8 (layer2 reuses: a_s2=[0..N), a_d2=[N..2N))
    float* a_d1 = a_s1 + (size_t)N * 8;       // N*8
    int*   deg  = (int*)(a_d1 + (size_t)N * 8); // N
    int*   offs = deg + N;                    // N
    int*   srcs = offs + N;                   // E
    int*   locx = srcs + E;                   // N (scan scratch)
    int*   bsum = locx + N;                   // nblk (scan scratch)
    double* bins = (double*)(((uintptr_t)(bsum + ((N + 255) / 256) + 1) + 7) & ~(uintptr_t)7);

    // rank[E] aliases bufB: dead before k_agg1 writes x. E <= N*64 required.
    int* rank = (int*)bufB;

    float* a_s2 = a_s1;
    float* a_d2 = a_s1 + N;

    float* out = (float*)d_out;

    const int nblk = (N + 255) / 256;
    const int egrid = (E + 255) / 256;

    hipMemsetAsync(deg, 0, (size_t)N * sizeof(int), stream);
    hipMemsetAsync(bins, 0, NBINS * sizeof(double), stream);

    // CSR build (rebuilt every call — no static state)
    k_hist <<<egrid, 256, 0, stream>>>(dst, deg, rank, E);
    k_scan1<<<nblk, 256, 0, stream>>>(deg, locx, bsum, N);
    k_scan2<<<1, 256, 0, stream>>>(bsum, nblk);
    k_scan3<<<nblk, 256, 0, stream>>>(locx, bsum, offs, N);
    k_fill <<<egrid, 256, 0, stream>>>(src, dst, rank, offs, srcs, E);

    k_gemm1<<<(N + 63) / 64, 256, 0, stream>>>(feat, W1, att_s1, att_d1, bufA, a_s1, a_d1, N);
    k_agg1 <<<(N + 3) / 4, 256, 0, stream>>>(deg, offs, srcs, a_s1, a_d1, bufA, b1, bufB, N);
    k_gemm2<<<(N + 63) / 64, 256, 0, stream>>>(bufB, W2, att_s2, att_d2, bufA, a_s2, a_d2, N);
    k_agg2 <<<(N + 3) / 4, 256, 0, stream>>>(deg, offs, srcs, a_s2, a_d2, bufA, b2, label,
                                             out, bins, N);
    k_loss <<<1, 256, 0, stream>>>(bins, out, N);
}